// Round 9
// baseline (121.457 us; speedup 1.0000x reference)
//
#include <hip/hip_runtime.h>

// SigScale: out[b, off_k + n] = x[b, off_k + n] * prod_{j} y[b, digit_j(n)]
// B=256, D=8, M=6, siglen = 299592 floats/row. Memory-bound (~614 MB HBM floor).
// Row byte pitch 1198368 ≡ 32 (mod 128) -> per-row quad phase s = (-2b)&7.
// R9: single variable vs R8 — grid.x 4 -> 2 (512 blocks, 2/CU), SEGQ 37440.
//     Ladder: NT +6us, contiguous geometry +3us, 8->4 blk/CU +1.5us.
//     NT load+store, batch 4, contiguous block sweep, lb(256,8) all kept.

#define SIGLEN 299592
#define NQ     74898   // SIGLEN / 4
#define SEGQ   37440   // quads per block segment (multiple of 8; 2*37440=74880, rest -> last block)

typedef float f4 __attribute__((ext_vector_type(4)));

__device__ __forceinline__ float quad_g(int q,
                                        const float* __restrict__ f1,
                                        const float* __restrict__ f2,
                                        const float* __restrict__ f3,
                                        int& nout) {
    const int pos = q << 2;   // float index within the row
    int n; float g;
    if (pos >= 37448) {            // level 6: prefix p = n>>3 has 15 bits
        n = pos - 37448; const int p = n >> 3; g = f3[p >> 6] * f2[p & 63];
    } else if (pos >= 4680) {      // level 5: prefix 12 bits
        n = pos - 4680;  const int p = n >> 3; g = f3[p >> 3] * f1[p & 7];
    } else if (pos >= 584) {       // level 4: prefix 9 bits
        n = pos - 584;   g = f3[n >> 3];
    } else if (pos >= 72) {        // level 3
        n = pos - 72;    g = f2[n >> 3];
    } else if (pos >= 8) {         // level 2
        n = pos - 8;     g = f1[n >> 3];
    } else {                       // level 1
        n = pos;         g = 1.0f;
    }
    nout = n;
    return g;
}

__global__ __launch_bounds__(256, 8) void sigscale_kernel(
    const float* __restrict__ x,
    const float* __restrict__ y,
    float* __restrict__ out)
{
    __shared__ __align__(16) float f1[8];   // y
    __shared__ float f2[64];                // y⊗y
    __shared__ float f3[512];               // y⊗y⊗y

    const int b   = blockIdx.y;
    const int tid = threadIdx.x;

    if (tid < 8) f1[tid] = y[b * 8 + tid];
    __syncthreads();
    if (tid < 64) f2[tid] = f1[tid >> 3] * f1[tid & 7];
    __syncthreads();
    for (int i = tid; i < 512; i += 256) f3[i] = f2[i >> 3] * f1[i & 7];
    __syncthreads();

    // low-digit factors in registers (no LDS read needed for the last digit)
    const f4 ylo = *reinterpret_cast<const f4*>(&f1[0]);
    const f4 yhi = *reinterpret_cast<const f4*>(&f1[4]);

    const f4* __restrict__ xr   = reinterpret_cast<const f4*>(x + (size_t)b * SIGLEN);
    f4* __restrict__       orow = reinterpret_cast<f4*>(out + (size_t)b * SIGLEN);

    // phase shift so bulk accesses are 128B-aligned: (32*b + 16*s) % 128 == 0
    const int s = (-(b << 1)) & 7;

    // head quads [0, s) — levels 1..2 only, handled by block x==0
    if (blockIdx.x == 0 && tid < s) {
        const int q = tid;
        int n; const float g = quad_g(q, f1, f2, f3, n);
        const f4 yl = (n & 4) ? yhi : ylo;
        orow[q] = xr[q] * (g * yl);
    }

    // contiguous per-block segment [segb, sege), base ≡ s (mod 8)
    const int segb = s + blockIdx.x * SEGQ;
    const int sege = (blockIdx.x == 1) ? NQ : segb + SEGQ;

    constexpr int STRIDE = 256;           // block-wide step (4 KB)
    constexpr int BATCH  = 4;
    constexpr int SPAN   = BATCH * STRIDE; // 1024 quads = 16 KB contiguous per batch

    int q = segb + tid;

    // main loop: 4 NT loads (16 KB contiguous per block), then 4 NT stores
    for (; q + (BATCH - 1) * STRIDE < sege; q += SPAN) {
        f4 v[BATCH];
        #pragma unroll
        for (int j = 0; j < BATCH; ++j)
            v[j] = __builtin_nontemporal_load(&xr[q + j * STRIDE]);
        #pragma unroll
        for (int j = 0; j < BATCH; ++j) {
            int n; const float g = quad_g(q + j * STRIDE, f1, f2, f3, n);
            const f4 a = (n & 4) ? yhi : ylo;
            __builtin_nontemporal_store(v[j] * (g * a), &orow[q + j * STRIDE]);
        }
    }

    // tail singles
    for (; q < sege; q += STRIDE) {
        int n; const float g = quad_g(q, f1, f2, f3, n);
        const f4 yl = (n & 4) ? yhi : ylo;
        const f4 t = __builtin_nontemporal_load(&xr[q]);
        __builtin_nontemporal_store(t * (g * yl), &orow[q]);
    }
}

extern "C" void kernel_launch(void* const* d_in, const int* in_sizes, int n_in,
                              void* d_out, int out_size, void* d_ws, size_t ws_size,
                              hipStream_t stream) {
    const float* x = (const float*)d_in[0];
    const float* y = (const float*)d_in[1];
    float* out = (float*)d_out;

    dim3 grid(2, 256);   // 512 blocks = 2 blocks/CU: halve concurrent DRAM streams again
    sigscale_kernel<<<grid, 256, 0, stream>>>(x, y, out);
}

// Round 10
// 119.887 us; speedup vs baseline: 1.0131x; 1.0131x over previous
//
#include <hip/hip_runtime.h>

// SigScale: out[b, off_k + n] = x[b, off_k + n] * prod_{j} y[b, digit_j(n)]
// B=256, D=8, M=6, siglen = 299592 floats/row. Memory-bound (~614 MB HBM floor).
// Row byte pitch 1198368 ≡ 32 (mod 128) -> per-row quad phase s = (-2b)&7.
// R10: REVERT to R8 (measured optimum, 119.4 us ≈ 5.14 TB/s = 82% of copy ceiling).
//     Ladder: NT +6us, contiguous geometry +3us, 8->4 blk/CU +1.5us, 2/CU regressed.
//     grid 4x256, SEGQ 18720, NT load+store, batch 4, contiguous sweep, lb(256,8).

#define SIGLEN 299592
#define NQ     74898   // SIGLEN / 4
#define SEGQ   18720   // quads per block segment (multiple of 8; 4*18720=74880, rest -> last block)

typedef float f4 __attribute__((ext_vector_type(4)));

__device__ __forceinline__ float quad_g(int q,
                                        const float* __restrict__ f1,
                                        const float* __restrict__ f2,
                                        const float* __restrict__ f3,
                                        int& nout) {
    const int pos = q << 2;   // float index within the row
    int n; float g;
    if (pos >= 37448) {            // level 6: prefix p = n>>3 has 15 bits
        n = pos - 37448; const int p = n >> 3; g = f3[p >> 6] * f2[p & 63];
    } else if (pos >= 4680) {      // level 5: prefix 12 bits
        n = pos - 4680;  const int p = n >> 3; g = f3[p >> 3] * f1[p & 7];
    } else if (pos >= 584) {       // level 4: prefix 9 bits
        n = pos - 584;   g = f3[n >> 3];
    } else if (pos >= 72) {        // level 3
        n = pos - 72;    g = f2[n >> 3];
    } else if (pos >= 8) {         // level 2
        n = pos - 8;     g = f1[n >> 3];
    } else {                       // level 1
        n = pos;         g = 1.0f;
    }
    nout = n;
    return g;
}

__global__ __launch_bounds__(256, 8) void sigscale_kernel(
    const float* __restrict__ x,
    const float* __restrict__ y,
    float* __restrict__ out)
{
    __shared__ __align__(16) float f1[8];   // y
    __shared__ float f2[64];                // y⊗y
    __shared__ float f3[512];               // y⊗y⊗y

    const int b   = blockIdx.y;
    const int tid = threadIdx.x;

    if (tid < 8) f1[tid] = y[b * 8 + tid];
    __syncthreads();
    if (tid < 64) f2[tid] = f1[tid >> 3] * f1[tid & 7];
    __syncthreads();
    for (int i = tid; i < 512; i += 256) f3[i] = f2[i >> 3] * f1[i & 7];
    __syncthreads();

    // low-digit factors in registers (no LDS read needed for the last digit)
    const f4 ylo = *reinterpret_cast<const f4*>(&f1[0]);
    const f4 yhi = *reinterpret_cast<const f4*>(&f1[4]);

    const f4* __restrict__ xr   = reinterpret_cast<const f4*>(x + (size_t)b * SIGLEN);
    f4* __restrict__       orow = reinterpret_cast<f4*>(out + (size_t)b * SIGLEN);

    // phase shift so bulk accesses are 128B-aligned: (32*b + 16*s) % 128 == 0
    const int s = (-(b << 1)) & 7;

    // head quads [0, s) — levels 1..2 only, handled by block x==0
    if (blockIdx.x == 0 && tid < s) {
        const int q = tid;
        int n; const float g = quad_g(q, f1, f2, f3, n);
        const f4 yl = (n & 4) ? yhi : ylo;
        orow[q] = xr[q] * (g * yl);
    }

    // contiguous per-block segment [segb, sege), base ≡ s (mod 8)
    const int segb = s + blockIdx.x * SEGQ;
    const int sege = (blockIdx.x == 3) ? NQ : segb + SEGQ;

    constexpr int STRIDE = 256;           // block-wide step (4 KB)
    constexpr int BATCH  = 4;
    constexpr int SPAN   = BATCH * STRIDE; // 1024 quads = 16 KB contiguous per batch

    int q = segb + tid;

    // main loop: 4 NT loads (16 KB contiguous per block), then 4 NT stores
    for (; q + (BATCH - 1) * STRIDE < sege; q += SPAN) {
        f4 v[BATCH];
        #pragma unroll
        for (int j = 0; j < BATCH; ++j)
            v[j] = __builtin_nontemporal_load(&xr[q + j * STRIDE]);
        #pragma unroll
        for (int j = 0; j < BATCH; ++j) {
            int n; const float g = quad_g(q + j * STRIDE, f1, f2, f3, n);
            const f4 a = (n & 4) ? yhi : ylo;
            __builtin_nontemporal_store(v[j] * (g * a), &orow[q + j * STRIDE]);
        }
    }

    // tail singles
    for (; q < sege; q += STRIDE) {
        int n; const float g = quad_g(q, f1, f2, f3, n);
        const f4 yl = (n & 4) ? yhi : ylo;
        const f4 t = __builtin_nontemporal_load(&xr[q]);
        __builtin_nontemporal_store(t * (g * yl), &orow[q]);
    }
}

extern "C" void kernel_launch(void* const* d_in, const int* in_sizes, int n_in,
                              void* d_out, int out_size, void* d_ws, size_t ws_size,
                              hipStream_t stream) {
    const float* x = (const float*)d_in[0];
    const float* y = (const float*)d_in[1];
    float* out = (float*)d_out;

    dim3 grid(4, 256);   // 1024 blocks = 4 blocks/CU (measured optimum)
    sigscale_kernel<<<grid, 256, 0, stream>>>(x, y, out);
}